// Round 2
// baseline (3166.998 us; speedup 1.0000x reference)
//
#include <hip/hip_runtime.h>

typedef _Float16 f16;
typedef __attribute__((ext_vector_type(8))) _Float16 f16x8;
typedef __attribute__((ext_vector_type(4))) float f32x4;

#define D_      300
#define L_      5
#define MAXN_   96
#define NGRAPH  4096
#define SELF_BOND 4
#define MAXDEG  32

// ---------------- weight prep: transpose + pad + f32->f16 ----------------
// W1t[l][j<608][k<320] = W1[l][k][j];  W2t[l][c<304][k<608] = W2[l][k][c]
__global__ void k_prep_w(const float* __restrict__ W1, const float* __restrict__ W2,
                         f16* __restrict__ W1t, f16* __restrict__ W2t) {
  const int T1 = L_ * 608 * 320;
  const int T2 = L_ * 304 * 608;
  for (int idx = blockIdx.x * blockDim.x + threadIdx.x; idx < T1 + T2;
       idx += gridDim.x * blockDim.x) {
    if (idx < T1) {
      int l = idx / (608 * 320), r = idx % (608 * 320);
      int j = r / 320, k = r % 320;
      W1t[idx] = (j < 600 && k < 300) ? (f16)W1[(l * 300 + k) * 600 + j] : (f16)0.0f;
    } else {
      int i2 = idx - T1;
      int l = i2 / (304 * 608), r = i2 % (304 * 608);
      int c = r / 608, k = r % 608;
      W2t[i2] = (c < 300 && k < 600) ? (f16)W2[(l * 600 + k) * 300 + c] : (f16)0.0f;
    }
  }
}

// ---------------- graph bookkeeping ----------------
__global__ void k_bc_init(int* counts, int* offsets) {
  int i = blockIdx.x * blockDim.x + threadIdx.x;
  if (i < NGRAPH) { counts[i] = 0; offsets[i] = 0x7fffffff; }
}
__global__ void k_zero_i32(int* p, int n) {
  for (int i = blockIdx.x * blockDim.x + threadIdx.x; i < n; i += gridDim.x * blockDim.x)
    p[i] = 0;
}
__global__ void k_bc_count(const int* __restrict__ batch, int n, int* counts, int* offsets) {
  int i = blockIdx.x * blockDim.x + threadIdx.x;
  if (i < n) { int b = batch[i]; atomicAdd(&counts[b], 1); atomicMin(&offsets[b], i); }
}
__global__ void k_pos(const int* __restrict__ batch, const int* __restrict__ offsets,
                      int n, int* __restrict__ pos) {
  int i = blockIdx.x * blockDim.x + threadIdx.x;
  if (i < n) pos[i] = i - offsets[batch[i]];
}
__global__ void k_mask(const int* __restrict__ counts, float* __restrict__ mask) {
  int i = blockIdx.x * blockDim.x + threadIdx.x;
  if (i < NGRAPH * MAXN_) {
    int b = i / MAXN_, j = i % MAXN_;
    mask[i] = (j >= counts[b]) ? 1.0f : 0.0f;
  }
}
__global__ void k_zero(uint4* __restrict__ p, int nchunks) {
  for (int i = blockIdx.x * blockDim.x + threadIdx.x; i < nchunks;
       i += gridDim.x * blockDim.x)
    p[i] = make_uint4(0u, 0u, 0u, 0u);
}

// ---------------- edge-slot table: incoming edges per dst node ----------------
__global__ void k_edges(const int* __restrict__ dst, int ne,
                        int* __restrict__ deg, int* __restrict__ eslot) {
  int e = blockIdx.x * blockDim.x + threadIdx.x;
  if (e < ne) {
    int t = dst[e];
    int p = atomicAdd(&deg[t], 1);
    if (p < MAXDEG) eslot[t * MAXDEG + p] = e;
  }
}

// ---------------- h0 = atom_emb1[x0] + atom_emb2[x1] (f32 in -> f16 ws) ----------------
__global__ void k_init_h(const int* __restrict__ x, const float* __restrict__ ae1,
                         const float* __restrict__ ae2, f16* __restrict__ h, int n) {
  long total = (long)n * 300;
  for (long idx = blockIdx.x * (long)blockDim.x + threadIdx.x; idx < total;
       idx += (long)gridDim.x * blockDim.x) {
    int i = idx / 300, d = idx % 300;
    int a1 = x[2 * i], a2 = x[2 * i + 1];
    h[idx] = (f16)(ae1[a1 * 300 + d] + ae2[a2 * 300 + d]);
  }
}

// ---------------- fused layer: gather + GEMM1 + relu + GEMM2 + BN ----------------
// 32 nodes / block, 512 threads (8 waves). LDS XOR-chunk swizzled (16B chunks).
__launch_bounds__(512, 2)
__global__ void k_layer(const f16* __restrict__ hin, f16* __restrict__ hout,
                        const int* __restrict__ src, const int* __restrict__ ea,
                        const int* __restrict__ deg, const int* __restrict__ eslot,
                        const float* __restrict__ ee1, const float* __restrict__ ee2,
                        const f16* __restrict__ W1t, const f16* __restrict__ W2t,
                        const float* __restrict__ b1, const float* __restrict__ b2,
                        const float* __restrict__ bng, const float* __restrict__ bnb,
                        const float* __restrict__ bnm, const float* __restrict__ bnv,
                        float* __restrict__ outp, const int* __restrict__ batch,
                        const int* __restrict__ pos, int last) {
  __shared__ f16 As[32 * 320];   // agg tile, K padded 300->320
  __shared__ f16 Hs[32 * 640];   // hidden tile, 608 cols in 640-wide swizzle rows
  const int tid = threadIdx.x;
  const int n0 = blockIdx.x * 32;
  const int w = tid >> 6, lane = tid & 63;

  // ---- phase A: gather agg = h[n] + self-loop-emb + sum_in (h[src]+e) ----
  const float* e1s = ee1 + SELF_BOND * 300;   // self-loop bond row
  const float* e2s = ee2;                     // dir 0 row
  for (int q = 0; q < 4; q++) {
    int ln = w * 4 + q;
    int n = n0 + ln;
    float acc[5];
#pragma unroll
    for (int k = 0; k < 5; k++) {
      int d = lane + 64 * k;
      acc[k] = (d < 300) ? ((float)hin[n * 300 + d] + e1s[d] + e2s[d]) : 0.0f;
    }
    int dg = deg[n]; if (dg > MAXDEG) dg = MAXDEG;
    for (int j = 0; j < dg; j++) {
      int e = eslot[n * MAXDEG + j];
      int s = src[e];
      int bo = ea[2 * e], di = ea[2 * e + 1];
      const f16* hr = hin + s * 300;
      const float* r1 = ee1 + bo * 300;
      const float* r2 = ee2 + di * 300;
#pragma unroll
      for (int k = 0; k < 5; k++) {
        int d = lane + 64 * k;
        if (d < 300) acc[k] += (float)hr[d] + r1[d] + r2[d];
      }
    }
#pragma unroll
    for (int k = 0; k < 5; k++) {
      int d = lane + 64 * k;
      float v = (d < 300) ? acc[k] : 0.0f;     // zero K-pad 300..319
      As[ln * 320 + ((((d >> 3) ^ (ln & 7))) << 3) + (d & 7)] = (f16)v;
    }
  }
  __syncthreads();

  const int lr = lane & 15, lk = lane >> 4;

  // ---- phase B: Hs = relu(As @ W1 + b1); 38 col-tiles of 16 ----
  for (int ct = w; ct < 38; ct += 8) {
    int col = ct * 16 + lr;
    const f16* bb = W1t + col * 320 + lk * 8;
    float b1v = (col < 600) ? b1[col] : 0.0f;
    f32x4 acc0 = {0, 0, 0, 0}, acc1 = {0, 0, 0, 0};
#pragma unroll
    for (int ks = 0; ks < 10; ks++) {
      f16x8 bf = *(const f16x8*)(bb + ks * 32);
      int kc = ks * 4 + lk;
      f16x8 a0 = *(const f16x8*)(As + lr * 320 + ((kc ^ (lr & 7)) << 3));
      int r1i = 16 + lr;
      f16x8 a1 = *(const f16x8*)(As + r1i * 320 + ((kc ^ (r1i & 7)) << 3));
      acc0 = __builtin_amdgcn_mfma_f32_16x16x32_f16(a0, bf, acc0, 0, 0, 0);
      acc1 = __builtin_amdgcn_mfma_f32_16x16x32_f16(a1, bf, acc1, 0, 0, 0);
    }
    int chc = col >> 3, co = col & 7;
#pragma unroll
    for (int i = 0; i < 4; i++) {
      int row0 = lk * 4 + i, row1 = 16 + lk * 4 + i;
      Hs[row0 * 640 + ((chc ^ (row0 & 7)) << 3) + co] = (f16)fmaxf(acc0[i] + b1v, 0.0f);
      Hs[row1 * 640 + ((chc ^ (row1 & 7)) << 3) + co] = (f16)fmaxf(acc1[i] + b1v, 0.0f);
    }
  }
  __syncthreads();

  // ---- phase C: out = BN(Hs @ W2 + b2); 19 col-tiles, K=608 ----
  for (int ct = w; ct < 19; ct += 8) {
    int col = ct * 16 + lr;
    const f16* bb = W2t + col * 608 + lk * 8;
    f32x4 acc0 = {0, 0, 0, 0}, acc1 = {0, 0, 0, 0};
#pragma unroll
    for (int ks = 0; ks < 19; ks++) {
      f16x8 bf = *(const f16x8*)(bb + ks * 32);
      int kc = ks * 4 + lk;
      f16x8 a0 = *(const f16x8*)(Hs + lr * 640 + ((kc ^ (lr & 7)) << 3));
      int r1i = 16 + lr;
      f16x8 a1 = *(const f16x8*)(Hs + r1i * 640 + ((kc ^ (r1i & 7)) << 3));
      acc0 = __builtin_amdgcn_mfma_f32_16x16x32_f16(a0, bf, acc0, 0, 0, 0);
      acc1 = __builtin_amdgcn_mfma_f32_16x16x32_f16(a1, bf, acc1, 0, 0, 0);
    }
    if (col < 300) {
      float b2v = b2[col];
      float sc = bng[col] * rsqrtf(bnv[col] + 1e-5f);
      float mu = bnm[col], be = bnb[col];
#pragma unroll
      for (int half = 0; half < 2; half++) {
        f32x4 acc = half ? acc1 : acc0;
#pragma unroll
        for (int i = 0; i < 4; i++) {
          int row = half * 16 + lk * 4 + i;
          int node = n0 + row;
          float v = (acc[i] + b2v - mu) * sc + be;
          if (!last) {
            v = fmaxf(v, 0.0f);
            hout[node * 300 + col] = (f16)v;
          } else {
            int g = batch[node], p = pos[node];
            if (p < MAXN_) outp[((long)g * MAXN_ + p) * 300 + col] = v;
          }
        }
      }
    }
  }
}

extern "C" void kernel_launch(void* const* d_in, const int* in_sizes, int n_in,
                              void* d_out, int out_size, void* d_ws, size_t ws_size,
                              hipStream_t stream) {
  const int* x     = (const int*)d_in[0];
  const int* ei    = (const int*)d_in[1];
  const int* ea    = (const int*)d_in[2];
  const int* batch = (const int*)d_in[3];
  const float* ae1 = (const float*)d_in[5];
  const float* ae2 = (const float*)d_in[6];
  const float* ee1 = (const float*)d_in[7];
  const float* ee2 = (const float*)d_in[8];
  const float* W1  = (const float*)d_in[9];
  const float* b1  = (const float*)d_in[10];
  const float* W2  = (const float*)d_in[11];
  const float* b2  = (const float*)d_in[12];
  const float* bng = (const float*)d_in[13];
  const float* bnb = (const float*)d_in[14];
  const float* bnm = (const float*)d_in[15];
  const float* bnv = (const float*)d_in[16];

  const int N = in_sizes[3];        // 131072
  const int E = in_sizes[2] / 2;    // 262144

  char* ws = (char*)d_ws;
  f16* hA    = (f16*)ws;                         //  78,643,200 B
  f16* hB    = (f16*)(ws + 78643200);            //  78,643,200 B
  f16* W1t   = (f16*)(ws + 157286400);           //   1,945,600 B
  f16* W2t   = (f16*)(ws + 159232000);           //   1,848,320 B
  int* deg   = (int*)(ws + 161080320);           //     524,288 B
  int* eslot = (int*)(ws + 161604608);           //  16,777,216 B
  int* pos   = (int*)(ws + 178381824);           //     524,288 B
  int* counts= (int*)(ws + 178906112);           //      16,384 B
  int* offs  = (int*)(ws + 178922496);           //      16,384 B  (~179 MB total)

  float* outp  = (float*)d_out;
  float* maskp = outp + (long)NGRAPH * MAXN_ * D_;

  hipLaunchKernelGGL(k_prep_w, dim3(2048), dim3(256), 0, stream, W1, W2, W1t, W2t);
  hipLaunchKernelGGL(k_bc_init, dim3(16), dim3(256), 0, stream, counts, offs);
  hipLaunchKernelGGL(k_zero_i32, dim3(512), dim3(256), 0, stream, deg, N);
  hipLaunchKernelGGL(k_bc_count, dim3((N + 255) / 256), dim3(256), 0, stream, batch, N, counts, offs);
  hipLaunchKernelGGL(k_pos, dim3((N + 255) / 256), dim3(256), 0, stream, batch, offs, N, pos);
  hipLaunchKernelGGL(k_mask, dim3((NGRAPH * MAXN_ + 255) / 256), dim3(256), 0, stream, counts, maskp);
  hipLaunchKernelGGL(k_edges, dim3((E + 255) / 256), dim3(256), 0, stream, ei + E, E, deg, eslot);
  hipLaunchKernelGGL(k_zero, dim3(4096), dim3(256), 0, stream,
                     (uint4*)outp, NGRAPH * MAXN_ * D_ / 4);
  hipLaunchKernelGGL(k_init_h, dim3(4096), dim3(256), 0, stream, x, ae1, ae2, hA, N);

  for (int l = 0; l < L_; l++) {
    const f16* hi = (l & 1) ? hB : hA;
    f16*       ho = (l & 1) ? hA : hB;
    hipLaunchKernelGGL(k_layer, dim3(N / 32), dim3(512), 0, stream,
                       hi, ho, ei, ea, deg, eslot,
                       ee1 + l * 6 * 300, ee2 + l * 3 * 300,
                       W1t + l * 608 * 320, W2t + l * 304 * 608,
                       b1 + l * 600, b2 + l * 300,
                       bng + l * 300, bnb + l * 300, bnm + l * 300, bnv + l * 300,
                       outp, batch, pos, (l == L_ - 1) ? 1 : 0);
  }
}